// Round 2
// baseline (176.628 us; speedup 1.0000x reference)
//
#include <hip/hip_runtime.h>

#define B_DIM   4096
#define IN_DIM  4096
#define OUT_DIM 4096

// One WAVE per row (no LDS, no __syncthreads). 4 waves/block -> 4 rows/block,
// 2048 blocks for the 8192 rows (4096 input + 4096 weight).
// Each lane: 16 unrolled float4 loads (256 B/lane, 64 lanes * 16 B = 1 KB
// per instruction, fully coalesced), 4 independent accumulators for ILP,
// then a 6-step shuffle reduction across the 64-lane wave.
// Weight rows are pre-multiplied by bias[o] so the epilogue is one FMA.
__global__ __launch_bounds__(256) void rowsum_kernel(
    const float* __restrict__ input, const float* __restrict__ weight,
    const float* __restrict__ bias, float* __restrict__ ws)
{
    const int wave = threadIdx.x >> 6;
    const int lane = threadIdx.x & 63;
    const int row  = blockIdx.x * 4 + wave;          // 0 .. 8191

    const float* src = (row < B_DIM)
        ? input  + (size_t)row * IN_DIM
        : weight + (size_t)(row - B_DIM) * IN_DIM;
    const float4* src4 = (const float4*)src;         // 1024 float4 per row

    float s0 = 0.f, s1 = 0.f, s2 = 0.f, s3 = 0.f;
    #pragma unroll
    for (int k = 0; k < 16; k += 4) {                // 16 loads in flight
        float4 v0 = src4[lane + (k + 0) * 64];
        float4 v1 = src4[lane + (k + 1) * 64];
        float4 v2 = src4[lane + (k + 2) * 64];
        float4 v3 = src4[lane + (k + 3) * 64];
        s0 += (v0.x + v0.y) + (v0.z + v0.w);
        s1 += (v1.x + v1.y) + (v1.z + v1.w);
        s2 += (v2.x + v2.y) + (v2.z + v2.w);
        s3 += (v3.x + v3.y) + (v3.z + v3.w);
    }
    float s = (s0 + s1) + (s2 + s3);

    #pragma unroll
    for (int off = 32; off > 0; off >>= 1)
        s += __shfl_down(s, off, 64);

    if (lane == 0) {
        if (row < B_DIM) {
            ws[row] = s;
        } else {
            const int o = row - B_DIM;
            ws[B_DIM + o] = s * bias[o];
        }
    }
}

// One block per output row: b = blockIdx.x is scalar, so ws[b] compiles to a
// wave-uniform s_load. bias / wb (16 KB each) are L1/L2-resident broadcast
// reads. 4 float4 stores per thread cover the row's 1024 float4s.
__global__ __launch_bounds__(256) void epilogue_kernel(
    const float* __restrict__ bias, const float* __restrict__ ws,
    float* __restrict__ out)
{
    const int b = blockIdx.x;
    const float xs = ws[b];

    const float4* bias4 = (const float4*)bias;
    const float4* wb4   = (const float4*)(ws + B_DIM);
    float4* out4 = (float4*)out + (size_t)b * (OUT_DIM / 4);

    #pragma unroll
    for (int k = 0; k < 4; ++k) {
        const int i = threadIdx.x + k * 256;
        const float4 bi = bias4[i];
        const float4 w  = wb4[i];
        float4 r;
        r.x = fmaf(xs, bi.x, w.x);
        r.y = fmaf(xs, bi.y, w.y);
        r.z = fmaf(xs, bi.z, w.z);
        r.w = fmaf(xs, bi.w, w.w);
        out4[i] = r;
    }
}

extern "C" void kernel_launch(void* const* d_in, const int* in_sizes, int n_in,
                              void* d_out, int out_size, void* d_ws, size_t ws_size,
                              hipStream_t stream) {
    const float* input  = (const float*)d_in[0];
    const float* weight = (const float*)d_in[1];
    const float* bias   = (const float*)d_in[2];
    float* out = (float*)d_out;
    float* ws  = (float*)d_ws;   // [0, B_DIM): x_sum; [B_DIM, B_DIM+OUT_DIM): bias*w_sum

    rowsum_kernel<<<(B_DIM + OUT_DIM) / 4, 256, 0, stream>>>(input, weight, bias, ws);
    epilogue_kernel<<<B_DIM, 256, 0, stream>>>(bias, ws, out);
}

// Round 4
// 170.186 us; speedup vs baseline: 1.0379x; 1.0379x over previous
//
#include <hip/hip_runtime.h>

#define B_DIM   4096
#define IN_DIM  4096
#define OUT_DIM 4096

typedef float floatx4 __attribute__((ext_vector_type(4)));  // native vec for nontemporal

// One WAVE per row. 4 waves/block, 2048 blocks for 8192 rows (input+weight).
// All 16 float4 loads land in an explicit array BEFORE any arithmetic,
// forcing ~64 VGPRs of load destinations and 16 back-to-back
// global_load_dwordx4 (deep MLP), vs the 32-VGPR / 4-deep schedule of R2.
__global__ __launch_bounds__(256) void rowsum_kernel(
    const float* __restrict__ input, const float* __restrict__ weight,
    const float* __restrict__ bias, float* __restrict__ ws)
{
    const int wave = threadIdx.x >> 6;
    const int lane = threadIdx.x & 63;
    const int row  = blockIdx.x * 4 + wave;          // 0 .. 8191

    const float* src = (row < B_DIM)
        ? input  + (size_t)row * IN_DIM
        : weight + (size_t)(row - B_DIM) * IN_DIM;
    const float4* src4 = (const float4*)src;         // 1024 float4 per row

    float4 v[16];
    #pragma unroll
    for (int k = 0; k < 16; ++k)                     // 16 loads in flight
        v[k] = src4[lane + k * 64];

    float s0 = 0.f, s1 = 0.f, s2 = 0.f, s3 = 0.f;
    #pragma unroll
    for (int k = 0; k < 16; k += 4) {
        s0 += (v[k+0].x + v[k+0].y) + (v[k+0].z + v[k+0].w);
        s1 += (v[k+1].x + v[k+1].y) + (v[k+1].z + v[k+1].w);
        s2 += (v[k+2].x + v[k+2].y) + (v[k+2].z + v[k+2].w);
        s3 += (v[k+3].x + v[k+3].y) + (v[k+3].z + v[k+3].w);
    }
    float s = (s0 + s1) + (s2 + s3);

    #pragma unroll
    for (int off = 32; off > 0; off >>= 1)
        s += __shfl_down(s, off, 64);

    if (lane == 0) {
        if (row < B_DIM) {
            ws[row] = s;
        } else {
            const int o = row - B_DIM;
            ws[B_DIM + o] = s * bias[o];
        }
    }
}

// One block per output row: ws[b] is wave-uniform; bias / wb (16 KB each) are
// L1/L2-resident. Nontemporal float4 stores: out is written once and never
// re-read — don't churn LLC dirty lines with 64 MB of streaming writes.
__global__ __launch_bounds__(256) void epilogue_kernel(
    const float* __restrict__ bias, const float* __restrict__ ws,
    float* __restrict__ out)
{
    const int b = blockIdx.x;
    const float xs = ws[b];

    const float4* bias4 = (const float4*)bias;
    const float4* wb4   = (const float4*)(ws + B_DIM);
    floatx4* out4 = (floatx4*)out + (size_t)b * (OUT_DIM / 4);

    #pragma unroll
    for (int k = 0; k < 4; ++k) {
        const int i = threadIdx.x + k * 256;
        const float4 bi = bias4[i];
        const float4 w  = wb4[i];
        floatx4 r;
        r.x = fmaf(xs, bi.x, w.x);
        r.y = fmaf(xs, bi.y, w.y);
        r.z = fmaf(xs, bi.z, w.z);
        r.w = fmaf(xs, bi.w, w.w);
        __builtin_nontemporal_store(r, &out4[i]);
    }
}

extern "C" void kernel_launch(void* const* d_in, const int* in_sizes, int n_in,
                              void* d_out, int out_size, void* d_ws, size_t ws_size,
                              hipStream_t stream) {
    const float* input  = (const float*)d_in[0];
    const float* weight = (const float*)d_in[1];
    const float* bias   = (const float*)d_in[2];
    float* out = (float*)d_out;
    float* ws  = (float*)d_ws;   // [0, B_DIM): x_sum; [B_DIM, B_DIM+OUT_DIM): bias*w_sum

    rowsum_kernel<<<(B_DIM + OUT_DIM) / 4, 256, 0, stream>>>(input, weight, bias, ws);
    epilogue_kernel<<<B_DIM, 256, 0, stream>>>(bias, ws, out);
}

// Round 5
// 163.396 us; speedup vs baseline: 1.0810x; 1.0416x over previous
//
#include <hip/hip_runtime.h>

#define B_DIM   4096
#define IN_DIM  4096
#define OUT_DIM 4096

typedef float floatx4 __attribute__((ext_vector_type(4)));

// Kernel A: wb[o] = bias[o] * sum_i weight[o,i]. One wave per weight row,
// 4 waves/block, 1024 blocks. Nontemporal loads: weight is streamed once,
// don't retain in L1/L2.
__global__ __launch_bounds__(256) void wsum_kernel(
    const float* __restrict__ weight, const float* __restrict__ bias,
    float* __restrict__ wb)
{
    const int wave = threadIdx.x >> 6;
    const int lane = threadIdx.x & 63;
    const int o    = blockIdx.x * 4 + wave;          // 0 .. 4095

    const floatx4* src4 = (const floatx4*)(weight + (size_t)o * IN_DIM);

    float s0 = 0.f, s1 = 0.f, s2 = 0.f, s3 = 0.f;
    #pragma unroll
    for (int k = 0; k < 16; k += 4) {
        floatx4 v0 = __builtin_nontemporal_load(&src4[lane + (k + 0) * 64]);
        floatx4 v1 = __builtin_nontemporal_load(&src4[lane + (k + 1) * 64]);
        floatx4 v2 = __builtin_nontemporal_load(&src4[lane + (k + 2) * 64]);
        floatx4 v3 = __builtin_nontemporal_load(&src4[lane + (k + 3) * 64]);
        s0 += (v0.x + v0.y) + (v0.z + v0.w);
        s1 += (v1.x + v1.y) + (v1.z + v1.w);
        s2 += (v2.x + v2.y) + (v2.z + v2.w);
        s3 += (v3.x + v3.y) + (v3.z + v3.w);
    }
    float s = (s0 + s1) + (s2 + s3);

    #pragma unroll
    for (int off = 32; off > 0; off >>= 1)
        s += __shfl_down(s, off, 64);

    if (lane == 0)
        wb[o] = s * bias[o];
}

// Kernel B (fused): one block per output row b.
//   phase 1: read input row b (16 KB, nontemporal), block-reduce -> xs
//   phase 2: out[b,:] = xs * bias[:] + wb[:]  (bias/wb are 16 KB each,
//            L2-resident after first touch), nontemporal stores.
// Across staggered blocks, phase-1 reads overlap phase-2 writes, so HBM sees
// a mixed read+write stream instead of two serial one-directional passes.
__global__ __launch_bounds__(256) void fused_kernel(
    const float* __restrict__ input, const float* __restrict__ bias,
    const float* __restrict__ wb, float* __restrict__ out)
{
    const int b = blockIdx.x;
    const int t = threadIdx.x;

    const floatx4* in4 = (const floatx4*)(input + (size_t)b * IN_DIM);

    floatx4 v[4];
    #pragma unroll
    for (int k = 0; k < 4; ++k)
        v[k] = __builtin_nontemporal_load(&in4[t + k * 256]);

    float s = 0.f;
    #pragma unroll
    for (int k = 0; k < 4; ++k)
        s += (v[k].x + v[k].y) + (v[k].z + v[k].w);

    #pragma unroll
    for (int off = 32; off > 0; off >>= 1)
        s += __shfl_down(s, off, 64);

    __shared__ float sm[4];
    if ((t & 63) == 0) sm[t >> 6] = s;
    __syncthreads();
    const float xs = (sm[0] + sm[1]) + (sm[2] + sm[3]);

    const floatx4* bias4 = (const floatx4*)bias;
    const floatx4* wb4   = (const floatx4*)wb;
    floatx4* out4 = (floatx4*)out + (size_t)b * (OUT_DIM / 4);

    #pragma unroll
    for (int k = 0; k < 4; ++k) {
        const int i = t + k * 256;
        const floatx4 bi = bias4[i];
        const floatx4 w  = wb4[i];
        floatx4 r;
        r.x = fmaf(xs, bi.x, w.x);
        r.y = fmaf(xs, bi.y, w.y);
        r.z = fmaf(xs, bi.z, w.z);
        r.w = fmaf(xs, bi.w, w.w);
        __builtin_nontemporal_store(r, &out4[i]);
    }
}

extern "C" void kernel_launch(void* const* d_in, const int* in_sizes, int n_in,
                              void* d_out, int out_size, void* d_ws, size_t ws_size,
                              hipStream_t stream) {
    const float* input  = (const float*)d_in[0];
    const float* weight = (const float*)d_in[1];
    const float* bias   = (const float*)d_in[2];
    float* out = (float*)d_out;
    float* wb  = (float*)d_ws;   // 4096 floats: bias[o] * w_sum[o]

    wsum_kernel<<<OUT_DIM / 4, 256, 0, stream>>>(weight, bias, wb);
    fused_kernel<<<B_DIM, 256, 0, stream>>>(input, bias, wb, out);
}